// Round 4
// baseline (289.205 us; speedup 1.0000x reference)
//
#include <hip/hip_runtime.h>
#include <hip/hip_bf16.h>

// Problem constants
#define Bb 2048
#define Tt 50
#define Vv 65
#define Ee 100
#define Hh 20
#define Dd 5

typedef __bf16 v8bf __attribute__((ext_vector_type(8)));
typedef short v8s __attribute__((ext_vector_type(8)));
typedef float f32x4 __attribute__((ext_vector_type(4)));

__device__ __forceinline__ v8bf bzero8() {
    v8s z = {0, 0, 0, 0, 0, 0, 0, 0};
    union { v8s s; v8bf b; } u; u.s = z; return u.b;
}
__device__ __forceinline__ unsigned short bfbits(float f) {
    union { __hip_bfloat16 h; unsigned short s; } c;
    c.h = __float2bfloat16(f);
    return c.s;
}

// ws layout (bytes)
#define WS_LOSS 0                        // 4B loss accum + 4B done counter
#define WS_WKQV 1024                     // [320][128] bf16 (k rows pre-scaled by 10*log2e)
#define WS_WFF  (1024 + 81920)           // [128][128] bf16
#define WS_WLM  (1024 + 81920 + 32768)   // [80][128] bf16

#define XSTRIDE 136                      // xpad row stride (bf16 elems), 16B-aligned rows

__global__ __launch_bounds__(256) void prep_kernel(
    const float* __restrict__ Wk, const float* __restrict__ Wq,
    const float* __restrict__ Wv, const float* __restrict__ Wff,
    const float* __restrict__ Wlm, char* __restrict__ ws)
{
    int g = blockIdx.x * 256 + threadIdx.x;
    if (g == 0) { *(float*)(ws + WS_LOSS) = 0.f; *(unsigned*)(ws + WS_LOSS + 4) = 0u; }
    __hip_bfloat16* wkqv = (__hip_bfloat16*)(ws + WS_WKQV);
    __hip_bfloat16* wff  = (__hip_bfloat16*)(ws + WS_WFF);
    __hip_bfloat16* wlm  = (__hip_bfloat16*)(ws + WS_WLM);
    if (g < 40960) {
        int n = g >> 7, e = g & 127;
        float v = 0.f;
        if (e < Ee) {
            if (n < 100)      v = Wk[n * Ee + e] * 14.4269504089f; // 10 * log2(e)
            else if (n < 200) v = Wq[(n - 100) * Ee + e];
            else if (n < 300) v = Wv[(n - 200) * Ee + e];
        }
        wkqv[g] = __float2bfloat16(v);
    } else if (g < 57344) {
        int gg = g - 40960; int n = gg >> 7, e = gg & 127;
        float v = (e < Ee && n < Ee) ? Wff[n * Ee + e] : 0.f;
        wff[gg] = __float2bfloat16(v);
    } else {
        int gg = g - 57344; int n = gg >> 7, e = gg & 127;
        float v = (e < Ee && n < Vv) ? Wlm[n * Ee + e] : 0.f;
        wlm[gg] = __float2bfloat16(v);
    }
}

__global__ __launch_bounds__(512, 4) void gpt_main(
    const int* __restrict__ idx, const int* __restrict__ targets,
    const float* __restrict__ tok_emb, const float* __restrict__ pos_emb,
    const float* __restrict__ b_ff, const float* __restrict__ b_lm,
    const char* __restrict__ ws, float* __restrict__ out,
    float* __restrict__ loss_acc, unsigned* __restrict__ done_cnt)
{
    // LDS total ~75.7 KB -> 2 blocks/CU (16 waves/CU)
    __shared__ __attribute__((aligned(16))) __hip_bfloat16 xpad[50 * XSTRIDE]; // x -> attn -> h (rows 0..49)
    __shared__ __attribute__((aligned(16))) __hip_bfloat16 kbuf[20 * 50 * 8];  // k' [h][t][8], d pads zero
    __shared__ __attribute__((aligned(16))) __hip_bfloat16 qbuf[20 * 50 * 8];  // q  [h][s][8], d pads zero
    __shared__ __attribute__((aligned(16))) __hip_bfloat16 vtb[20 * 5 * 64];   // v' [h][d][s], s>=50 zero
    __shared__ __attribute__((aligned(16))) __hip_bfloat16 sbuf[2 * 64 * 72];  // expS per head-group [g][t][72]
    __shared__ int tok_s[Tt];
    __shared__ float bsum;

    const int b    = blockIdx.x;
    const int tid  = threadIdx.x;
    const int wave = tid >> 6;
    const int ln   = tid & 15;
    const int quad = (tid >> 4) & 3;

    // ---- P1: stage idx; zero xpad/kbuf/qbuf/vtb; fill x = tok_emb[idx]+pos_emb ----
    if (tid < Tt) tok_s[tid] = idx[b * Tt + tid];
    if (tid == 0) bsum = 0.f;
    {
        const uint4 z4 = make_uint4(0u, 0u, 0u, 0u);
        for (int i = tid; i < 850; i += 512)  ((uint4*)xpad)[i] = z4;   // 13600B
        for (int i = tid; i < 1000; i += 512) ((uint4*)kbuf)[i] = z4;   // 16000B
        for (int i = tid; i < 1000; i += 512) ((uint4*)qbuf)[i] = z4;   // 16000B
        for (int i = tid; i < 800; i += 512)  ((uint4*)vtb)[i] = z4;    // 12800B
    }
    __syncthreads();
    for (int i = tid; i < Tt * 25; i += 512) {
        int r = i / 25, c4 = (i - r * 25) * 4;
        const float4 te = *(const float4*)&tok_emb[tok_s[r] * Ee + c4];
        const float4 pe = *(const float4*)&pos_emb[r * Ee + c4];
        ushort4 o;
        o.x = bfbits(te.x + pe.x); o.y = bfbits(te.y + pe.y);
        o.z = bfbits(te.z + pe.z); o.w = bfbits(te.w + pe.w);
        *(ushort4*)&xpad[r * XSTRIDE + c4] = o;
    }
    __syncthreads();

    // ---- P2: kqv = x @ Wkqv^T via MFMA (8 waves: 2 m-split x 4 n-split) ----
    {
        const __hip_bfloat16* wkqv = (const __hip_bfloat16*)(ws + WS_WKQV);
        const int mw = wave & 1, nw = wave >> 1;
        f32x4 acc[5][2];
#pragma unroll
        for (int ntl = 0; ntl < 5; ++ntl)
#pragma unroll
            for (int ml = 0; ml < 2; ++ml) {
                f32x4 z = {0.f, 0.f, 0.f, 0.f};
                acc[ntl][ml] = z;
            }
#pragma unroll
        for (int kt = 0; kt < 4; ++kt) {
            int r0 = (mw * 2 + 0) * 16 + ln;
            int r1 = (mw * 2 + 1) * 16 + ln;
            v8bf a0 = bzero8(), a1 = bzero8();
            if (r0 < Tt) a0 = *(const v8bf*)&xpad[r0 * XSTRIDE + kt * 32 + quad * 8];
            if (r1 < Tt) a1 = *(const v8bf*)&xpad[r1 * XSTRIDE + kt * 32 + quad * 8];
#pragma unroll
            for (int ntl = 0; ntl < 5; ++ntl) {
                v8bf bfr = *(const v8bf*)&wkqv[((nw * 5 + ntl) * 16 + ln) * 128 + kt * 32 + quad * 8];
                acc[ntl][0] = __builtin_amdgcn_mfma_f32_16x16x32_bf16(a0, bfr, acc[ntl][0], 0, 0, 0);
                acc[ntl][1] = __builtin_amdgcn_mfma_f32_16x16x32_bf16(a1, bfr, acc[ntl][1], 0, 0, 0);
            }
        }
        // C/D: col(n)=lane&15, row(m)=quad*4+reg
#pragma unroll
        for (int ntl = 0; ntl < 5; ++ntl) {
            int n = (nw * 5 + ntl) * 16 + ln;
            if (n < 300) {
                int mat = n / 100;
                int jj  = n - mat * 100;
                int h   = jj / 5, d = jj - (jj / 5) * 5;
#pragma unroll
                for (int ml = 0; ml < 2; ++ml)
#pragma unroll
                    for (int r = 0; r < 4; ++r) {
                        int m = (mw * 2 + ml) * 16 + quad * 4 + r;
                        if (m < Tt) {
                            __hip_bfloat16 val = __float2bfloat16(acc[ntl][ml][r]);
                            if (mat == 0)      kbuf[(h * 50 + m) * 8 + d] = val;
                            else if (mat == 1) qbuf[(h * 50 + m) * 8 + d] = val;
                            else               vtb[(h * 5 + d) * 64 + m] = val;
                        }
                    }
            }
        }
    }
    __syncthreads();

    // ---- P3: attention via MFMA, 2 heads per iteration ----
    for (int it = 0; it < 10; ++it) {
        const int h0 = it * 2;
        // QK^T -> masked exp2 -> sbuf (bf16). One K=32 MFMA per 16x16 tile.
        for (int j = wave; j < 32; j += 8) {
            int hg = j >> 4, tile = j & 15;
            int mt = tile >> 2, nt = tile & 3;
            int h = h0 + hg;
            f32x4 acc = {0.f, 0.f, 0.f, 0.f};
            bool lower = (mt >= nt);
            if (lower) {
                int trow = mt * 16 + ln, srow = nt * 16 + ln;
                v8bf a = bzero8(), bq = bzero8();
                if (quad == 0 && trow < Tt) a  = *(const v8bf*)&kbuf[(h * 50 + trow) * 8];
                if (quad == 0 && srow < Tt) bq = *(const v8bf*)&qbuf[(h * 50 + srow) * 8];
                acc = __builtin_amdgcn_mfma_f32_16x16x32_bf16(a, bq, acc, 0, 0, 0);
            }
            int sg = nt * 16 + ln;
            int tb = mt * 16 + quad * 4;
#pragma unroll
            for (int r = 0; r < 4; ++r) {
                int tg = tb + r;
                if (tg < Tt) {
                    float p = (lower && tg >= sg) ? __builtin_amdgcn_exp2f(acc[r]) : 0.f;
                    sbuf[hg * 4608 + tg * 72 + sg] = __float2bfloat16(p);
                }
            }
        }
        __syncthreads();
        // column denominators (softmax over t) + fold 1/denom into vtb
        if (tid < 400) {
            int col = tid >> 2, tc = tid & 3;
            int g = (col >= 50) ? 1 : 0;
            int s = col - g * 50;
            int sb = g * 4608 + s;
            float sum = 0.f;
            for (int t = tc; t < Tt; t += 4)
                sum += __bfloat162float(sbuf[sb + t * 72]);
            sum += __shfl_xor(sum, 1);
            sum += __shfl_xor(sum, 2);
            float rd = 1.0f / sum;
            int h = h0 + g;
            int vb = (h * 5 + tc) * 64 + s;
            vtb[vb] = __float2bfloat16(__bfloat162float(vtb[vb]) * rd);
            if (tc == 0) {
                int vb4 = (h * 5 + 4) * 64 + s;
                vtb[vb4] = __float2bfloat16(__bfloat162float(vtb[vb4]) * rd);
            }
        }
        __syncthreads();
        // PV: attn rows for this head-group -> xpad. 8 jobs = 2 heads x 4 m-tiles.
        {
            int hg = wave >> 2, mt = wave & 3;
            int h = h0 + hg;
            f32x4 acc = {0.f, 0.f, 0.f, 0.f};
#pragma unroll
            for (int kt = 0; kt < 2; ++kt) {
                v8bf a = *(const v8bf*)&sbuf[hg * 4608 + (mt * 16 + ln) * 72 + kt * 32 + quad * 8];
                v8bf bv = bzero8();
                if (ln < Dd) bv = *(const v8bf*)&vtb[(h * 5 + ln) * 64 + kt * 32 + quad * 8];
                acc = __builtin_amdgcn_mfma_f32_16x16x32_bf16(a, bv, acc, 0, 0, 0);
            }
            if (ln < Dd) {
#pragma unroll
                for (int r = 0; r < 4; ++r) {
                    int tg = mt * 16 + quad * 4 + r;
                    if (tg < Tt) xpad[tg * XSTRIDE + h * 5 + ln] = __float2bfloat16(acc[r]);
                }
            }
        }
        __syncthreads();
    }

    // ---- P4: h = relu(attn @ Wff^T + b_ff) via MFMA ----
    {
        const __hip_bfloat16* wff = (const __hip_bfloat16*)(ws + WS_WFF);
        f32x4 facc[4];
#pragma unroll
        for (int mt = 0; mt < 4; ++mt) { f32x4 z = {0.f, 0.f, 0.f, 0.f}; facc[mt] = z; }
        if (wave < 7) {
#pragma unroll
            for (int kt = 0; kt < 4; ++kt) {
                v8bf bfr = *(const v8bf*)&wff[(wave * 16 + ln) * 128 + kt * 32 + quad * 8];
#pragma unroll
                for (int mt = 0; mt < 4; ++mt) {
                    int row = mt * 16 + ln;
                    v8bf a = bzero8();
                    if (row < Tt) a = *(const v8bf*)&xpad[row * XSTRIDE + kt * 32 + quad * 8];
                    facc[mt] = __builtin_amdgcn_mfma_f32_16x16x32_bf16(a, bfr, facc[mt], 0, 0, 0);
                }
            }
        }
        __syncthreads();   // all attn reads done before overwriting xpad with h
        if (wave < 7) {
            int n = wave * 16 + ln;
            if (n < Ee) {
                float bias = b_ff[n];
#pragma unroll
                for (int mt = 0; mt < 4; ++mt)
#pragma unroll
                    for (int r = 0; r < 4; ++r) {
                        int m = mt * 16 + quad * 4 + r;
                        if (m < Tt) {
                            float v = facc[mt][r] + bias;
                            xpad[m * XSTRIDE + n] = __float2bfloat16(v > 0.f ? v : 0.f);
                        }
                    }
            }
        }
    }
    __syncthreads();

    // ---- P5: logits = h @ Wlm^T + b_lm via MFMA; 20 (mt,nt) jobs over 8 waves ----
    {
        const __hip_bfloat16* wlm = (const __hip_bfloat16*)(ws + WS_WLM);
        float* logits_lds = (float*)kbuf;   // kbuf dead; 50*68*4 = 13.6 KB <= 16 KB
        int jobs[3]; int nj = 2;
        jobs[0] = wave; jobs[1] = wave + 8; jobs[2] = 0;
        if (wave < 4) { jobs[2] = wave + 16; nj = 3; }
        for (int ji = 0; ji < nj; ++ji) {
            int j = jobs[ji];
            int mt = j / 5, nt = j - mt * 5;
            f32x4 acc = {0.f, 0.f, 0.f, 0.f};
#pragma unroll
            for (int kt = 0; kt < 4; ++kt) {
                int row = mt * 16 + ln;
                v8bf a = bzero8();
                if (row < Tt) a = *(const v8bf*)&xpad[row * XSTRIDE + kt * 32 + quad * 8];
                v8bf bf = *(const v8bf*)&wlm[(nt * 16 + ln) * 128 + kt * 32 + quad * 8];
                acc = __builtin_amdgcn_mfma_f32_16x16x32_bf16(a, bf, acc, 0, 0, 0);
            }
            int n = nt * 16 + ln;
            if (n < Vv) {
                float bias = b_lm[n];
#pragma unroll
                for (int r = 0; r < 4; ++r) {
                    int m = mt * 16 + quad * 4 + r;
                    if (m < Tt) {
                        float v = acc[r] + bias;
                        out[(b * Tt + m) * Vv + n] = v;
                        logits_lds[m * 68 + n] = v;
                    }
                }
            }
        }
    }
    __syncthreads();

    // ---- P6: loss; 8 lanes per token row ----
    if (tid < 400) {
        int r = tid >> 3, lv = tid & 7;
        const float* row = (const float*)kbuf + r * 68;
        float mx = -3.0e38f;
        for (int v = lv; v < Vv; v += 8) mx = fmaxf(mx, row[v]);
        mx = fmaxf(mx, __shfl_xor(mx, 1));
        mx = fmaxf(mx, __shfl_xor(mx, 2));
        mx = fmaxf(mx, __shfl_xor(mx, 4));
        float sum = 0.f;
        for (int v = lv; v < Vv; v += 8)
            sum += __builtin_amdgcn_exp2f((row[v] - mx) * 1.4426950408889634f);
        sum += __shfl_xor(sum, 1);
        sum += __shfl_xor(sum, 2);
        sum += __shfl_xor(sum, 4);
        if (lv == 0) {
            float lse = mx + 0.69314718055994531f * log2f(sum);
            int tgt = targets[b * Tt + r];
            atomicAdd(&bsum, lse - row[tgt]);
        }
    }
    __syncthreads();
    if (tid == 0) {
        atomicAdd(loss_acc, bsum);
        __threadfence();
        unsigned old = atomicAdd(done_cnt, 1u);
        if (old == (unsigned)(Bb - 1)) {       // last block finalizes the loss
            __threadfence();
            float total = atomicAdd(loss_acc, 0.0f);
            out[Bb * Tt * Vv] = total * (1.0f / (float)(Bb * Tt));
        }
    }
}

extern "C" void kernel_launch(void* const* d_in, const int* in_sizes, int n_in,
                              void* d_out, int out_size, void* d_ws, size_t ws_size,
                              hipStream_t stream)
{
    const int* idx     = (const int*)d_in[0];
    const int* targets = (const int*)d_in[1];
    const float* tok_emb = (const float*)d_in[2];
    const float* pos_emb = (const float*)d_in[3];
    const float* Wk  = (const float*)d_in[4];
    const float* Wq  = (const float*)d_in[5];
    const float* Wv  = (const float*)d_in[6];
    const float* Wff = (const float*)d_in[7];
    const float* bff = (const float*)d_in[8];
    const float* Wlm = (const float*)d_in[9];
    const float* blm = (const float*)d_in[10];
    float* out = (float*)d_out;
    char* ws = (char*)d_ws;
    float* loss_acc = (float*)(ws + WS_LOSS);
    unsigned* done_cnt = (unsigned*)(ws + WS_LOSS + 4);

    hipLaunchKernelGGL(prep_kernel, dim3(264), dim3(256), 0, stream, Wk, Wq, Wv, Wff, Wlm, ws);
    hipLaunchKernelGGL(gpt_main, dim3(Bb), dim3(512), 0, stream,
                       idx, targets, tok_emb, pos_emb, bff, blm, (const char*)ws, out,
                       loss_acc, done_cnt);
}

// Round 6
// 250.925 us; speedup vs baseline: 1.1526x; 1.1526x over previous
//
#include <hip/hip_runtime.h>
#include <hip/hip_bf16.h>

// Problem constants
#define Bb 2048
#define Tt 50
#define Vv 65
#define Ee 100
#define Hh 20
#define Dd 5

typedef __bf16 v8bf __attribute__((ext_vector_type(8)));
typedef short v8s __attribute__((ext_vector_type(8)));
typedef float f32x4 __attribute__((ext_vector_type(4)));

__device__ __forceinline__ v8bf bzero8() {
    v8s z = {0, 0, 0, 0, 0, 0, 0, 0};
    union { v8s s; v8bf b; } u; u.s = z; return u.b;
}
__device__ __forceinline__ unsigned short bfbits(float f) {
    union { __hip_bfloat16 h; unsigned short s; } c;
    c.h = __float2bfloat16(f);
    return c.s;
}
__device__ __forceinline__ unsigned pack2(float a, float b) {
    return (unsigned)bfbits(a) | ((unsigned)bfbits(b) << 16);
}

// ws layout (bytes)
#define WS_LOSS 0                        // 4B loss accum + 4B done counter
#define WS_WKQV 1024                     // [320][128] bf16 (k rows pre-scaled by 10*log2e)
#define WS_WFF  (1024 + 81920)           // [128][128] bf16
#define WS_WLM  (1024 + 81920 + 32768)   // [80][128] bf16

#define XSTR 136                         // x/attn/h row stride (bf16 elems), 16B-aligned rows

__global__ __launch_bounds__(256) void prep_kernel(
    const float* __restrict__ Wk, const float* __restrict__ Wq,
    const float* __restrict__ Wv, const float* __restrict__ Wff,
    const float* __restrict__ Wlm, char* __restrict__ ws)
{
    int g = blockIdx.x * 256 + threadIdx.x;
    if (g == 0) { *(float*)(ws + WS_LOSS) = 0.f; *(unsigned*)(ws + WS_LOSS + 4) = 0u; }
    __hip_bfloat16* wkqv = (__hip_bfloat16*)(ws + WS_WKQV);
    __hip_bfloat16* wff  = (__hip_bfloat16*)(ws + WS_WFF);
    __hip_bfloat16* wlm  = (__hip_bfloat16*)(ws + WS_WLM);
    if (g < 40960) {
        int n = g >> 7, e = g & 127;
        float v = 0.f;
        if (e < Ee) {
            if (n < 100)      v = Wk[n * Ee + e] * 14.4269504089f; // 10 * log2(e)
            else if (n < 200) v = Wq[(n - 100) * Ee + e];
            else if (n < 300) v = Wv[(n - 200) * Ee + e];
        }
        wkqv[g] = __float2bfloat16(v);
    } else if (g < 57344) {
        int gg = g - 40960; int n = gg >> 7, e = gg & 127;
        float v = (e < Ee && n < Ee) ? Wff[n * Ee + e] : 0.f;
        wff[gg] = __float2bfloat16(v);
    } else {
        int gg = g - 57344; int n = gg >> 7, e = gg & 127;
        float v = (e < Ee && n < Vv) ? Wlm[n * Ee + e] : 0.f;
        wlm[gg] = __float2bfloat16(v);
    }
}

__global__ __launch_bounds__(256, 2) void gpt_main(
    const int* __restrict__ idx, const int* __restrict__ targets,
    const float* __restrict__ tok_emb, const float* __restrict__ pos_emb,
    const float* __restrict__ b_ff, const float* __restrict__ b_lm,
    const char* __restrict__ ws, float* __restrict__ out,
    float* __restrict__ loss_acc, unsigned* __restrict__ done_cnt)
{
    // LDS 76.7KB -> 2 blocks/CU. Region overlays:
    //  regA: x[50][136] -> E[wave][64][64] (swizzled) -> h[50][136] + logits f32 [50][68]
    //  regB: qb[20][50][8]@0 + kb[20][50][8]@8000 -> attnbuf[50][136]
    __shared__ __attribute__((aligned(16))) __hip_bfloat16 regA[16384];
    __shared__ __attribute__((aligned(16))) __hip_bfloat16 regB[16384];
    __shared__ __attribute__((aligned(16))) __hip_bfloat16 vtb[6400];   // v' [h][d][64], s>=50 zero
    __shared__ int tok_s[Tt];
    __shared__ float bsum;

    const int b      = blockIdx.x;
    const int tid    = threadIdx.x;
    const int wave   = tid >> 6;
    const int lane64 = tid & 63;
    const int ln     = tid & 15;
    const int quad   = (tid >> 4) & 3;

    // ---- P1: stage idx; zero regA/regB/vtb FULLY (LDS garbage is lethal); fill x ----
    if (tid < Tt) tok_s[tid] = idx[b * Tt + tid];
    if (tid == 0) bsum = 0.f;
    {
        const uint4 z4 = make_uint4(0u, 0u, 0u, 0u);
        for (int i = tid; i < 1024; i += 256) ((uint4*)regA)[i] = z4;   // full 32768B
        for (int i = tid; i < 2048; i += 256) ((uint4*)regB)[i] = z4;   // full 32768B
        for (int i = tid; i < 800; i += 256)  ((uint4*)vtb)[i] = z4;    // full 12800B
    }
    __syncthreads();
    for (int i = tid; i < Tt * 25; i += 256) {
        int r = i / 25, c4 = (i - r * 25) * 4;
        const float4 te = *(const float4*)&tok_emb[tok_s[r] * Ee + c4];
        const float4 pe = *(const float4*)&pos_emb[r * Ee + c4];
        ushort4 o;
        o.x = bfbits(te.x + pe.x); o.y = bfbits(te.y + pe.y);
        o.z = bfbits(te.z + pe.z); o.w = bfbits(te.w + pe.w);
        *(ushort4*)&regA[r * XSTR + c4] = o;
    }
    __syncthreads();

    // ---- P2: kqv = x @ Wkqv^T via MFMA (4 waves x 5 n-tiles x 4 m-tiles) ----
    {
        const __hip_bfloat16* wkqv = (const __hip_bfloat16*)(ws + WS_WKQV);
        f32x4 acc[5][4];
#pragma unroll
        for (int j = 0; j < 5; ++j)
#pragma unroll
            for (int mt = 0; mt < 4; ++mt) {
                f32x4 z = {0.f, 0.f, 0.f, 0.f};
                acc[j][mt] = z;
            }
#pragma unroll
        for (int kt = 0; kt < 4; ++kt) {
            v8bf a[4];
#pragma unroll
            for (int mt = 0; mt < 4; ++mt)
                a[mt] = *(const v8bf*)&regA[(mt * 16 + ln) * XSTR + kt * 32 + quad * 8];
#pragma unroll
            for (int j = 0; j < 5; ++j) {
                int nt = wave * 5 + j;
                v8bf bfr = *(const v8bf*)&wkqv[(nt * 16 + ln) * 128 + kt * 32 + quad * 8];
#pragma unroll
                for (int mt = 0; mt < 4; ++mt)
                    acc[j][mt] = __builtin_amdgcn_mfma_f32_16x16x32_bf16(a[mt], bfr, acc[j][mt], 0, 0, 0);
            }
        }
        // C/D: col(n)=ln, row(m)=quad*4+r
#pragma unroll
        for (int j = 0; j < 5; ++j) {
            int n = (wave * 5 + j) * 16 + ln;
            if (n < 300) {
                int mat = n / 100;
                int jj  = n - mat * 100;
                int h   = jj / 5, d = jj - (jj / 5) * 5;
#pragma unroll
                for (int mt = 0; mt < 4; ++mt)
#pragma unroll
                    for (int r = 0; r < 4; ++r) {
                        int m = mt * 16 + quad * 4 + r;
                        if (m < Tt) {
                            __hip_bfloat16 val = __float2bfloat16(acc[j][mt][r]);
                            if (mat == 0)      regB[8000 + (h * 50 + m) * 8 + d] = val; // kb
                            else if (mat == 1) regB[(h * 50 + m) * 8 + d] = val;        // qb
                            else               vtb[(h * 5 + d) * 64 + m] = val;
                        }
                    }
            }
        }
    }
    __syncthreads();

    // ---- P3: attention, one wave per head, barrier-free. D1[s][t] = q_s . k'_t ----
    unsigned attp[5][8];   // packed bf16 attn results, held until post-barrier dump
    {
        __hip_bfloat16* Ew = regA + wave * 4096;   // private [64][64], XOR-swizzled cols
        // zero the whole private E buffer ONCE: upper-triangle tiles are never
        // stored by pass 1 but ARE read by pass 2's MFMA — they must be 0, not
        // stale x / LDS garbage (R5's 2e37 bug). Zeros persist across all 5 heads.
        {
            const uint4 z4 = make_uint4(0u, 0u, 0u, 0u);
#pragma unroll
            for (int i = 0; i < 8; ++i)
                ((uint4*)Ew)[lane64 + i * 64] = z4;
        }
#pragma unroll
        for (int hj = 0; hj < 5; ++hj) {
            const int h = wave * 5 + hj;
            // load q/k fragments (quad 0 carries d=0..7; pads are zero)
            v8bf qf[4], kf[4];
#pragma unroll
            for (int i = 0; i < 4; ++i) {
                int row = i * 16 + ln;
                qf[i] = (quad == 0) ? *(const v8bf*)&regB[(h * 50 + row) * 8] : bzero8();
                kf[i] = (quad == 0) ? *(const v8bf*)&regB[8000 + (h * 50 + row) * 8] : bzero8();
            }
            // pass 1: per s-tile row: MFMA tiles, mask+exp, in-reg denom, scale, b64 store
#pragma unroll
            for (int ms = 0; ms < 4; ++ms) {
                f32x4 tac[4];
#pragma unroll
                for (int u = 0; u < 4; ++u) {
                    if (u < 4 - ms) {
                        f32x4 z = {0.f, 0.f, 0.f, 0.f};
                        tac[u] = __builtin_amdgcn_mfma_f32_16x16x32_bf16(qf[ms], kf[ms + u], z, 0, 0, 0);
                    }
                }
                const int sbase = ms * 16 + quad * 4;
                float e[4][4];
                float rsum[4] = {0.f, 0.f, 0.f, 0.f};
#pragma unroll
                for (int u = 0; u < 4; ++u) {
                    if (u < 4 - ms) {
                        int t = (ms + u) * 16 + ln;
#pragma unroll
                        for (int r = 0; r < 4; ++r) {
                            int s = sbase + r;
                            float x = __builtin_amdgcn_exp2f(tac[u][r]);
                            x = (t >= s && t < Tt && s < Tt) ? x : 0.f;
                            e[u][r] = x;
                            rsum[r] += x;
                        }
                    }
                }
                float rd[4];
#pragma unroll
                for (int r = 0; r < 4; ++r) {
                    float v = rsum[r];
                    v += __shfl_xor(v, 1); v += __shfl_xor(v, 2);
                    v += __shfl_xor(v, 4); v += __shfl_xor(v, 8);
                    rd[r] = ((sbase + r) < Tt) ? 1.0f / v : 0.f;
                }
#pragma unroll
                for (int u = 0; u < 4; ++u) {
                    if (u < 4 - ms) {
                        int t = (ms + u) * 16 + ln;
                        int swc = sbase ^ ((t & 7) << 3);
                        ushort4 o;
                        o.x = bfbits(e[u][0] * rd[0]); o.y = bfbits(e[u][1] * rd[1]);
                        o.z = bfbits(e[u][2] * rd[2]); o.w = bfbits(e[u][3] * rd[3]);
                        *(ushort4*)&Ew[t * 64 + swc] = o;
                    }
                }
            }
            // pass 2: PV. D[t][d] = sum_s E[t][s] * v'[d][s]; results stay in regs
#pragma unroll
            for (int mt = 0; mt < 4; ++mt) {
                f32x4 pac = {0.f, 0.f, 0.f, 0.f};
                int t = mt * 16 + ln;
#pragma unroll
                for (int kt = 0; kt < 2; ++kt) {
                    int swc = (kt * 32 + quad * 8) ^ ((t & 7) << 3);
                    v8bf a  = *(const v8bf*)&Ew[t * 64 + swc];
                    v8bf bv = (ln < Dd) ? *(const v8bf*)&vtb[(h * 5 + ln) * 64 + kt * 32 + quad * 8]
                                        : bzero8();
                    pac = __builtin_amdgcn_mfma_f32_16x16x32_bf16(a, bv, pac, 0, 0, 0);
                }
                attp[hj][mt * 2]     = pack2(pac[0], pac[1]);
                attp[hj][mt * 2 + 1] = pack2(pac[2], pac[3]);
            }
        }
    }
    __syncthreads();   // all attention done; qb/kb and E dead

    // ---- dump attn registers -> attnbuf (regB, rows [50][136]) ----
#pragma unroll
    for (int hj = 0; hj < 5; ++hj) {
        int col = (wave * 5 + hj) * 5 + ln;
#pragma unroll
        for (int mt = 0; mt < 4; ++mt)
#pragma unroll
            for (int r = 0; r < 4; ++r) {
                int t = mt * 16 + quad * 4 + r;
                if (ln < Dd && t < Tt) {
                    unsigned w = attp[hj][mt * 2 + (r >> 1)];
                    unsigned short v = (unsigned short)((r & 1) ? (w >> 16) : (w & 0xffff));
                    *(unsigned short*)&regB[t * XSTR + col] = v;
                }
            }
    }
    __syncthreads();

    // ---- P4: h = relu(attn @ Wff^T + b_ff); h -> regA[50][136] ----
    {
        const __hip_bfloat16* wff = (const __hip_bfloat16*)(ws + WS_WFF);
        f32x4 fac[2][4];
#pragma unroll
        for (int u = 0; u < 2; ++u)
#pragma unroll
            for (int mt = 0; mt < 4; ++mt) {
                f32x4 z = {0.f, 0.f, 0.f, 0.f};
                fac[u][mt] = z;
            }
        const int nn = (wave < 3) ? 2 : 1;
#pragma unroll
        for (int kt = 0; kt < 4; ++kt) {
            v8bf a[4];
#pragma unroll
            for (int mt = 0; mt < 4; ++mt)
                a[mt] = *(const v8bf*)&regB[(mt * 16 + ln) * XSTR + kt * 32 + quad * 8];
#pragma unroll
            for (int u = 0; u < 2; ++u) {
                if (u < nn) {
                    int nt = wave + u * 4;
                    v8bf bfr = *(const v8bf*)&wff[(nt * 16 + ln) * 128 + kt * 32 + quad * 8];
#pragma unroll
                    for (int mt = 0; mt < 4; ++mt)
                        fac[u][mt] = __builtin_amdgcn_mfma_f32_16x16x32_bf16(a[mt], bfr, fac[u][mt], 0, 0, 0);
                }
            }
        }
#pragma unroll
        for (int u = 0; u < 2; ++u) {
            if (u < nn) {
                int n = (wave + u * 4) * 16 + ln;
                if (n < Ee) {
                    float bias = b_ff[n];
#pragma unroll
                    for (int mt = 0; mt < 4; ++mt)
#pragma unroll
                        for (int r = 0; r < 4; ++r) {
                            int m = mt * 16 + quad * 4 + r;
                            if (m < Tt) {
                                float v = fac[u][mt][r] + bias;
                                regA[m * XSTR + n] = __float2bfloat16(v > 0.f ? v : 0.f);
                            }
                        }
                }
            }
        }
    }
    __syncthreads();

    // ---- P5: logits = h @ Wlm^T + b_lm; global f32 + LDS f32 ----
    {
        const __hip_bfloat16* wlm = (const __hip_bfloat16*)(ws + WS_WLM);
        float* lgl = (float*)(regA + 6800);   // byte 13600, [50][68] f32
#pragma unroll
        for (int i = 0; i < 5; ++i) {
            int job = wave + i * 4;            // 0..19
            int mt = job / 5, nt = job - (job / 5) * 5;
            f32x4 acc = {0.f, 0.f, 0.f, 0.f};
#pragma unroll
            for (int kt = 0; kt < 4; ++kt) {
                v8bf a  = *(const v8bf*)&regA[(mt * 16 + ln) * XSTR + kt * 32 + quad * 8];
                v8bf bf = *(const v8bf*)&wlm[(nt * 16 + ln) * 128 + kt * 32 + quad * 8];
                acc = __builtin_amdgcn_mfma_f32_16x16x32_bf16(a, bf, acc, 0, 0, 0);
            }
            int n = nt * 16 + ln;
            if (n < Vv) {
                float bias = b_lm[n];
#pragma unroll
                for (int r = 0; r < 4; ++r) {
                    int m = mt * 16 + quad * 4 + r;
                    if (m < Tt) {
                        float v = acc[r] + bias;
                        out[(b * Tt + m) * Vv + n] = v;
                        lgl[m * 68 + n] = v;
                    }
                }
            }
        }
    }
    __syncthreads();

    // ---- P6: loss; 4 lanes per token row ----
    if (tid < 200) {
        int r = tid >> 2, lv = tid & 3;
        const float* row = (const float*)(regA + 6800) + r * 68;
        float mx = -3.0e38f;
        for (int v = lv; v < Vv; v += 4) mx = fmaxf(mx, row[v]);
        mx = fmaxf(mx, __shfl_xor(mx, 1));
        mx = fmaxf(mx, __shfl_xor(mx, 2));
        float sum = 0.f;
        for (int v = lv; v < Vv; v += 4)
            sum += __builtin_amdgcn_exp2f((row[v] - mx) * 1.4426950408889634f);
        sum += __shfl_xor(sum, 1);
        sum += __shfl_xor(sum, 2);
        if (lv == 0) {
            float lse = mx + 0.69314718055994531f * log2f(sum);
            int tgt = targets[b * Tt + r];
            atomicAdd(&bsum, lse - row[tgt]);
        }
    }
    __syncthreads();
    if (tid == 0) {
        atomicAdd(loss_acc, bsum);
        __threadfence();
        unsigned old = atomicAdd(done_cnt, 1u);
        if (old == (unsigned)(Bb - 1)) {       // last block finalizes the loss
            __threadfence();
            float total = atomicAdd(loss_acc, 0.0f);
            out[Bb * Tt * Vv] = total * (1.0f / (float)(Bb * Tt));
        }
    }
}

extern "C" void kernel_launch(void* const* d_in, const int* in_sizes, int n_in,
                              void* d_out, int out_size, void* d_ws, size_t ws_size,
                              hipStream_t stream)
{
    const int* idx     = (const int*)d_in[0];
    const int* targets = (const int*)d_in[1];
    const float* tok_emb = (const float*)d_in[2];
    const float* pos_emb = (const float*)d_in[3];
    const float* Wk  = (const float*)d_in[4];
    const float* Wq  = (const float*)d_in[5];
    const float* Wv  = (const float*)d_in[6];
    const float* Wff = (const float*)d_in[7];
    const float* bff = (const float*)d_in[8];
    const float* Wlm = (const float*)d_in[9];
    const float* blm = (const float*)d_in[10];
    float* out = (float*)d_out;
    char* ws = (char*)d_ws;
    float* loss_acc = (float*)(ws + WS_LOSS);
    unsigned* done_cnt = (unsigned*)(ws + WS_LOSS + 4);

    hipLaunchKernelGGL(prep_kernel, dim3(264), dim3(256), 0, stream, Wk, Wq, Wv, Wff, Wlm, ws);
    hipLaunchKernelGGL(gpt_main, dim3(Bb), dim3(256), 0, stream,
                       idx, targets, tok_emb, pos_emb, bff, blm, (const char*)ws, out,
                       loss_acc, done_cnt);
}

// Round 7
// 226.591 us; speedup vs baseline: 1.2763x; 1.1074x over previous
//
#include <hip/hip_runtime.h>
#include <hip/hip_bf16.h>

// Problem constants
#define Bb 2048
#define Tt 50
#define Vv 65
#define Ee 100
#define Hh 20
#define Dd 5

typedef __bf16 v8bf __attribute__((ext_vector_type(8)));
typedef short v8s __attribute__((ext_vector_type(8)));
typedef short v4s __attribute__((ext_vector_type(4)));
typedef float f32x4 __attribute__((ext_vector_type(4)));

__device__ __forceinline__ v8bf bzero8() {
    v8s z = {0, 0, 0, 0, 0, 0, 0, 0};
    union { v8s s; v8bf b; } u; u.s = z; return u.b;
}
__device__ __forceinline__ unsigned short bfbits(float f) {
    union { __hip_bfloat16 h; unsigned short s; } c;
    c.h = __float2bfloat16(f);
    return c.s;
}
__device__ __forceinline__ unsigned pack2(float a, float b) {
    return (unsigned)bfbits(a) | ((unsigned)bfbits(b) << 16);
}

// K=16 bf16 MFMA: builtin if present, else raw encoding via asm (ISA §10).
__device__ __forceinline__ f32x4 mfma_16x16x16_bf16(v4s a, v4s b, f32x4 c) {
#if __has_builtin(__builtin_amdgcn_mfma_f32_16x16x16bf16_1k)
    return __builtin_amdgcn_mfma_f32_16x16x16bf16_1k(a, b, c, 0, 0, 0);
#else
    f32x4 d;
    asm volatile("v_mfma_f32_16x16x16_bf16 %0, %1, %2, %3\n\ts_nop 7\n\ts_nop 4"
                 : "=v"(d) : "v"(a), "v"(b), "v"(c));
    return d;
#endif
}

// ws layout (bytes)
#define WS_LOSS 0                        // 4B loss accum + 4B done counter
#define WS_WKQV 1024                     // [320][128] bf16 (k rows pre-scaled by 10*log2e)
#define WS_WFF  (1024 + 81920)           // [128][128] bf16
#define WS_WLM  (1024 + 81920 + 32768)   // [80][128] bf16

#define XSTR 136                         // x/attn/h row stride (bf16 elems)
// shared overlays (bf16 element offsets into sh[]):
//  region1 @0     (8000 elems): x[50][136] -> qb[20][50][8] -> attnbuf[50][136] -> logits f32[50][68]
//  region2 @8000  (8000 elems): kb[20][50][8] -> h[50][136]
//  region3 @16000 (6400 elems): vtb[20][5][64] (raw v, s>=50 zero)
#define R2 8000
#define R3 16000

__global__ __launch_bounds__(256) void prep_kernel(
    const float* __restrict__ Wk, const float* __restrict__ Wq,
    const float* __restrict__ Wv, const float* __restrict__ Wff,
    const float* __restrict__ Wlm, char* __restrict__ ws)
{
    int g = blockIdx.x * 256 + threadIdx.x;
    if (g == 0) { *(float*)(ws + WS_LOSS) = 0.f; *(unsigned*)(ws + WS_LOSS + 4) = 0u; }
    __hip_bfloat16* wkqv = (__hip_bfloat16*)(ws + WS_WKQV);
    __hip_bfloat16* wff  = (__hip_bfloat16*)(ws + WS_WFF);
    __hip_bfloat16* wlm  = (__hip_bfloat16*)(ws + WS_WLM);
    if (g < 40960) {
        int n = g >> 7, e = g & 127;
        float v = 0.f;
        if (e < Ee) {
            if (n < 100)      v = Wk[n * Ee + e] * 14.4269504089f; // 10 * log2(e)
            else if (n < 200) v = Wq[(n - 100) * Ee + e];
            else if (n < 300) v = Wv[(n - 200) * Ee + e];
        }
        wkqv[g] = __float2bfloat16(v);
    } else if (g < 57344) {
        int gg = g - 40960; int n = gg >> 7, e = gg & 127;
        float v = (e < Ee && n < Ee) ? Wff[n * Ee + e] : 0.f;
        wff[gg] = __float2bfloat16(v);
    } else {
        int gg = g - 57344; int n = gg >> 7, e = gg & 127;
        float v = (e < Ee && n < Vv) ? Wlm[n * Ee + e] : 0.f;
        wlm[gg] = __float2bfloat16(v);
    }
}

__global__ __launch_bounds__(256, 3) void gpt_main(
    const int* __restrict__ idx, const int* __restrict__ targets,
    const float* __restrict__ tok_emb, const float* __restrict__ pos_emb,
    const float* __restrict__ b_ff, const float* __restrict__ b_lm,
    const char* __restrict__ ws, float* __restrict__ out,
    float* __restrict__ loss_acc, unsigned* __restrict__ done_cnt)
{
    __shared__ __attribute__((aligned(16))) __hip_bfloat16 sh[22400];  // 44.8 KB -> 3 blocks/CU
    __shared__ int tok_s[Tt];
    __shared__ float bsum;

    const int b    = blockIdx.x;
    const int tid  = threadIdx.x;
    const int wave = tid >> 6;
    const int ln   = tid & 15;
    const int quad = (tid >> 4) & 3;

    // ---- P1: stage idx; zero ALL of sh; fill x = tok_emb[idx]+pos_emb ----
    if (tid < Tt) tok_s[tid] = idx[b * Tt + tid];
    if (tid == 0) bsum = 0.f;
    {
        const uint4 z4 = make_uint4(0u, 0u, 0u, 0u);
        for (int i = tid; i < 2800; i += 256) ((uint4*)sh)[i] = z4;
    }
    __syncthreads();
    for (int i = tid; i < Tt * 25; i += 256) {
        int r = i / 25, c4 = (i - r * 25) * 4;
        const float4 te = *(const float4*)&tok_emb[tok_s[r] * Ee + c4];
        const float4 pe = *(const float4*)&pos_emb[r * Ee + c4];
        ushort4 o;
        o.x = bfbits(te.x + pe.x); o.y = bfbits(te.y + pe.y);
        o.z = bfbits(te.z + pe.z); o.w = bfbits(te.w + pe.w);
        *(ushort4*)&sh[r * XSTR + c4] = o;
    }
    __syncthreads();

    // ---- P2: kqv = x @ Wkqv^T via MFMA (4 waves x 5 n-tiles x 4 m-tiles) ----
    {
        const __hip_bfloat16* wkqv = (const __hip_bfloat16*)(ws + WS_WKQV);
        f32x4 acc[5][4];
#pragma unroll
        for (int j = 0; j < 5; ++j)
#pragma unroll
            for (int mt = 0; mt < 4; ++mt) {
                f32x4 z = {0.f, 0.f, 0.f, 0.f};
                acc[j][mt] = z;
            }
#pragma unroll
        for (int kt = 0; kt < 4; ++kt) {
            v8bf a[4];
#pragma unroll
            for (int mt = 0; mt < 4; ++mt)
                a[mt] = (mt < 3 || ln < 2)   // row < 50 only (x has 50 rows now)
                      ? *(const v8bf*)&sh[(mt * 16 + ln) * XSTR + kt * 32 + quad * 8]
                      : bzero8();
#pragma unroll
            for (int j = 0; j < 5; ++j) {
                int nt = wave * 5 + j;
                v8bf bfr = *(const v8bf*)&wkqv[(nt * 16 + ln) * 128 + kt * 32 + quad * 8];
#pragma unroll
                for (int mt = 0; mt < 4; ++mt)
                    acc[j][mt] = __builtin_amdgcn_mfma_f32_16x16x32_bf16(a[mt], bfr, acc[j][mt], 0, 0, 0);
            }
        }
        __syncthreads();   // all x reads done; region1 becomes qb
        // re-zero qb d-pads (bytes 10..15 of each 16B row) — stale x data otherwise
        for (int i = tid; i < 1000; i += 256) {
            *(unsigned short*)&sh[i * 8 + 5] = 0;
            *(unsigned*)&sh[i * 8 + 6] = 0;
        }
        // C/D: col(n)=ln, row(m)=quad*4+r
#pragma unroll
        for (int j = 0; j < 5; ++j) {
            int n = (wave * 5 + j) * 16 + ln;
            if (n < 300) {
                int mat = n / 100;
                int jj  = n - mat * 100;
                int h   = jj / 5, d = jj - (jj / 5) * 5;
#pragma unroll
                for (int mt = 0; mt < 4; ++mt)
#pragma unroll
                    for (int r = 0; r < 4; ++r) {
                        int m = mt * 16 + quad * 4 + r;
                        if (m < Tt) {
                            __hip_bfloat16 val = __float2bfloat16(acc[j][mt][r]);
                            if (mat == 0)      sh[R2 + (h * 50 + m) * 8 + d] = val;  // kb
                            else if (mat == 1) sh[(h * 50 + m) * 8 + d] = val;       // qb
                            else               sh[R3 + (h * 5 + d) * 64 + m] = val;  // vtb
                        }
                    }
            }
        }
    }
    __syncthreads();

    // ---- P3: attention fully in-register. QK^T: D1[s][t]=q_s.k'_t (K=32);
    //      mask+exp+column-denominator in-reg; PV via K=16 MFMA (e-frags are
    //      already in A-layout: A[m=t=ln][k=s=quad*4+j]). No E buffer at all. ----
    unsigned attp[5][8];
    {
#pragma unroll
        for (int hj = 0; hj < 5; ++hj) {
            const int h = wave * 5 + hj;
            v8bf qf[4], kf[4];
#pragma unroll
            for (int i = 0; i < 4; ++i) {
                int row = i * 16 + ln;
                qf[i] = (quad == 0) ? *(const v8bf*)&sh[(h * 50 + row) * 8] : bzero8();
                kf[i] = (quad == 0) ? *(const v8bf*)&sh[R2 + (h * 50 + row) * 8] : bzero8();
            }
            f32x4 pac[4];
#pragma unroll
            for (int mt = 0; mt < 4; ++mt) { f32x4 z = {0.f, 0.f, 0.f, 0.f}; pac[mt] = z; }
#pragma unroll
            for (int ms = 0; ms < 4; ++ms) {
                f32x4 tac[4];
#pragma unroll
                for (int u = 0; u < 4 - ms; ++u) {
                    f32x4 z = {0.f, 0.f, 0.f, 0.f};
                    tac[u] = __builtin_amdgcn_mfma_f32_16x16x32_bf16(qf[ms], kf[ms + u], z, 0, 0, 0);
                }
                const int sbase = ms * 16 + quad * 4;
                float e[4][4];
                float rsum[4] = {0.f, 0.f, 0.f, 0.f};
#pragma unroll
                for (int u = 0; u < 4 - ms; ++u) {
                    int t = (ms + u) * 16 + ln;
#pragma unroll
                    for (int r = 0; r < 4; ++r) {
                        int s = sbase + r;
                        float x = __builtin_amdgcn_exp2f(tac[u][r]);
                        x = (t >= s && t < Tt && s < Tt) ? x : 0.f;
                        e[u][r] = x;
                        rsum[r] += x;
                    }
                }
                float rd[4];
#pragma unroll
                for (int r = 0; r < 4; ++r) {
                    float v = rsum[r];
                    v += __shfl_xor(v, 1); v += __shfl_xor(v, 2);
                    v += __shfl_xor(v, 4); v += __shfl_xor(v, 8);
                    rd[r] = ((sbase + r) < Tt) ? __builtin_amdgcn_rcpf(v) : 0.f;
                }
                // B-frag: B[k=s=quad*4+j][n=d=ln] = v[s][d] from vtb
                v4s bvt;
                if (ln < Dd) bvt = *(const v4s*)&sh[R3 + (h * 5 + ln) * 64 + ms * 16 + quad * 4];
                else { v4s z = {0, 0, 0, 0}; bvt = z; }
#pragma unroll
                for (int u = 0; u < 4 - ms; ++u) {
                    v4s af;
                    af[0] = (short)bfbits(e[u][0] * rd[0]);
                    af[1] = (short)bfbits(e[u][1] * rd[1]);
                    af[2] = (short)bfbits(e[u][2] * rd[2]);
                    af[3] = (short)bfbits(e[u][3] * rd[3]);
                    pac[ms + u] = mfma_16x16x16_bf16(af, bvt, pac[ms + u]);
                }
            }
            // C/D of 16x16x16: col n=ln (d), row m=quad*4+r -> t = mt*16+quad*4+r
#pragma unroll
            for (int mt = 0; mt < 4; ++mt) {
                attp[hj][mt * 2]     = pack2(pac[mt][0], pac[mt][1]);
                attp[hj][mt * 2 + 1] = pack2(pac[mt][2], pac[mt][3]);
            }
        }
    }
    __syncthreads();   // all qb/kb/vtb reads done; region1 becomes attnbuf

    // ---- dump attn registers -> attnbuf (region1, [50][136]) ----
#pragma unroll
    for (int hj = 0; hj < 5; ++hj) {
        int col = (wave * 5 + hj) * 5 + ln;
#pragma unroll
        for (int mt = 0; mt < 4; ++mt)
#pragma unroll
            for (int r = 0; r < 4; ++r) {
                int t = mt * 16 + quad * 4 + r;
                if (ln < Dd && t < Tt) {
                    unsigned w = attp[hj][mt * 2 + (r >> 1)];
                    unsigned short v = (unsigned short)((r & 1) ? (w >> 16) : (w & 0xffff));
                    *(unsigned short*)&sh[t * XSTR + col] = v;
                }
            }
    }
    __syncthreads();

    // ---- P4: h = relu(attn @ Wff^T + b_ff); attnbuf(region1) -> h(region2) ----
    {
        const __hip_bfloat16* wff = (const __hip_bfloat16*)(ws + WS_WFF);
        f32x4 fac[2][4];
#pragma unroll
        for (int u = 0; u < 2; ++u)
#pragma unroll
            for (int mt = 0; mt < 4; ++mt) {
                f32x4 z = {0.f, 0.f, 0.f, 0.f};
                fac[u][mt] = z;
            }
        const int nn = (wave < 3) ? 2 : 1;
#pragma unroll
        for (int kt = 0; kt < 4; ++kt) {
            v8bf a[4];
#pragma unroll
            for (int mt = 0; mt < 4; ++mt)
                a[mt] = (mt < 3 || ln < 2)
                      ? *(const v8bf*)&sh[(mt * 16 + ln) * XSTR + kt * 32 + quad * 8]
                      : bzero8();
#pragma unroll
            for (int u = 0; u < 2; ++u) {
                if (u < nn) {
                    int nt = wave + u * 4;
                    v8bf bfr = *(const v8bf*)&wff[(nt * 16 + ln) * 128 + kt * 32 + quad * 8];
#pragma unroll
                    for (int mt = 0; mt < 4; ++mt)
                        fac[u][mt] = __builtin_amdgcn_mfma_f32_16x16x32_bf16(a[mt], bfr, fac[u][mt], 0, 0, 0);
                }
            }
        }
#pragma unroll
        for (int u = 0; u < 2; ++u) {
            if (u < nn) {
                int n = (wave + u * 4) * 16 + ln;
                if (n < Ee) {
                    float bias = b_ff[n];
#pragma unroll
                    for (int mt = 0; mt < 4; ++mt)
#pragma unroll
                        for (int r = 0; r < 4; ++r) {
                            int m = mt * 16 + quad * 4 + r;
                            if (m < Tt) {
                                float v = fac[u][mt][r] + bias;
                                sh[R2 + m * XSTR + n] = __float2bfloat16(v > 0.f ? v : 0.f);
                            }
                        }
                }
            }
        }
    }
    __syncthreads();

    // ---- P5: logits = h @ Wlm^T + b_lm; h(region2) -> out + logits f32(region1) ----
    {
        const __hip_bfloat16* wlm = (const __hip_bfloat16*)(ws + WS_WLM);
        float* lgl = (float*)sh;   // [50][68] f32 = 13600B
#pragma unroll
        for (int i = 0; i < 5; ++i) {
            int job = wave + i * 4;            // 0..19
            int mt = job / 5, nt = job - (job / 5) * 5;
            f32x4 acc = {0.f, 0.f, 0.f, 0.f};
#pragma unroll
            for (int kt = 0; kt < 4; ++kt) {
                v8bf a = (mt < 3 || ln < 2)
                       ? *(const v8bf*)&sh[R2 + (mt * 16 + ln) * XSTR + kt * 32 + quad * 8]
                       : bzero8();
                v8bf bf = *(const v8bf*)&wlm[(nt * 16 + ln) * 128 + kt * 32 + quad * 8];
                acc = __builtin_amdgcn_mfma_f32_16x16x32_bf16(a, bf, acc, 0, 0, 0);
            }
            int n = nt * 16 + ln;
            if (n < Vv) {
                float bias = b_lm[n];
#pragma unroll
                for (int r = 0; r < 4; ++r) {
                    int m = mt * 16 + quad * 4 + r;
                    if (m < Tt) {
                        float v = acc[r] + bias;
                        out[(b * Tt + m) * Vv + n] = v;
                        lgl[m * 68 + n] = v;
                    }
                }
            }
        }
    }
    __syncthreads();

    // ---- P6: loss; 4 lanes per token row ----
    if (tid < 200) {
        int r = tid >> 2, lv = tid & 3;
        const float* row = (const float*)sh + r * 68;
        float mx = -3.0e38f;
        for (int v = lv; v < Vv; v += 4) mx = fmaxf(mx, row[v]);
        mx = fmaxf(mx, __shfl_xor(mx, 1));
        mx = fmaxf(mx, __shfl_xor(mx, 2));
        float sum = 0.f;
        for (int v = lv; v < Vv; v += 4)
            sum += __builtin_amdgcn_exp2f((row[v] - mx) * 1.4426950408889634f);
        sum += __shfl_xor(sum, 1);
        sum += __shfl_xor(sum, 2);
        if (lv == 0) {
            float lse = mx + 0.69314718055994531f * log2f(sum);
            int tgt = targets[b * Tt + r];
            atomicAdd(&bsum, lse - row[tgt]);
        }
    }
    __syncthreads();
    if (tid == 0) {
        atomicAdd(loss_acc, bsum);
        __threadfence();
        unsigned old = atomicAdd(done_cnt, 1u);
        if (old == (unsigned)(Bb - 1)) {       // last block finalizes the loss
            __threadfence();
            float total = atomicAdd(loss_acc, 0.0f);
            out[Bb * Tt * Vv] = total * (1.0f / (float)(Bb * Tt));
        }
    }
}

extern "C" void kernel_launch(void* const* d_in, const int* in_sizes, int n_in,
                              void* d_out, int out_size, void* d_ws, size_t ws_size,
                              hipStream_t stream)
{
    const int* idx     = (const int*)d_in[0];
    const int* targets = (const int*)d_in[1];
    const float* tok_emb = (const float*)d_in[2];
    const float* pos_emb = (const float*)d_in[3];
    const float* Wk  = (const float*)d_in[4];
    const float* Wq  = (const float*)d_in[5];
    const float* Wv  = (const float*)d_in[6];
    const float* Wff = (const float*)d_in[7];
    const float* bff = (const float*)d_in[8];
    const float* Wlm = (const float*)d_in[9];
    const float* blm = (const float*)d_in[10];
    float* out = (float*)d_out;
    char* ws = (char*)d_ws;
    float* loss_acc = (float*)(ws + WS_LOSS);
    unsigned* done_cnt = (unsigned*)(ws + WS_LOSS + 4);

    hipLaunchKernelGGL(prep_kernel, dim3(264), dim3(256), 0, stream, Wk, Wq, Wv, Wff, Wlm, ws);
    hipLaunchKernelGGL(gpt_main, dim3(Bb), dim3(256), 0, stream,
                       idx, targets, tok_emb, pos_emb, bff, blm, (const char*)ws, out,
                       loss_acc, done_cnt);
}

// Round 8
// 188.082 us; speedup vs baseline: 1.5377x; 1.2047x over previous
//
#include <hip/hip_runtime.h>
#include <hip/hip_bf16.h>

// Problem constants
#define Bb 2048
#define Tt 50
#define Vv 65
#define Ee 100
#define Hh 20
#define Dd 5

typedef __bf16 v8bf __attribute__((ext_vector_type(8)));
typedef short v8s __attribute__((ext_vector_type(8)));
typedef short v4s __attribute__((ext_vector_type(4)));
typedef float f32x4 __attribute__((ext_vector_type(4)));

__device__ __forceinline__ v8bf bzero8() {
    v8s z = {0, 0, 0, 0, 0, 0, 0, 0};
    union { v8s s; v8bf b; } u; u.s = z; return u.b;
}
__device__ __forceinline__ unsigned short bfbits(float f) {
    union { __hip_bfloat16 h; unsigned short s; } c;
    c.h = __float2bfloat16(f);
    return c.s;
}
__device__ __forceinline__ float bf2f(short s) {
    union { unsigned i; float f; } c; c.i = ((unsigned)(unsigned short)s) << 16; return c.f;
}
__device__ __forceinline__ unsigned pack2(float a, float b) {
    return (unsigned)bfbits(a) | ((unsigned)bfbits(b) << 16);
}

// K=16 bf16 MFMA (validated on HW in R7)
__device__ __forceinline__ f32x4 mfma_16x16x16_bf16(v4s a, v4s b, f32x4 c) {
#if __has_builtin(__builtin_amdgcn_mfma_f32_16x16x16bf16_1k)
    return __builtin_amdgcn_mfma_f32_16x16x16bf16_1k(a, b, c, 0, 0, 0);
#else
    f32x4 d;
    asm volatile("v_mfma_f32_16x16x16_bf16 %0, %1, %2, %3\n\ts_nop 7\n\ts_nop 4"
                 : "=v"(d) : "v"(a), "v"(b), "v"(c));
    return d;
#endif
}

// ws layout (bytes)
#define WS_WKQV 1024                     // [320][128] bf16 (k rows pre-scaled by 10*log2e)
#define WS_WFF  (1024 + 81920)           // [128][128] bf16
#define WS_WLM  (1024 + 81920 + 32768)   // [80][128] bf16
#define WS_LPART (1024 + 81920 + 32768 + 20480)  // 2048 f32 per-block loss partials

#define XSTR 136                         // x/attn/h row stride (bf16 elems)
// shared overlays (bf16 element offsets into sh[]):
//  region1 @0     (8000): x[50][136] -> qb[20][50][8] -> attnbuf[50][136] -> logits f32[50][68]
//  region2 @8000  (8000): kb[20][50][8] -> h[50][136]
//  region3 @16000 (6400): vtb[20][5][64] (raw v, s>=50 zero)
#define R2 8000
#define R3 16000

__global__ __launch_bounds__(256) void prep_kernel(
    const float* __restrict__ Wk, const float* __restrict__ Wq,
    const float* __restrict__ Wv, const float* __restrict__ Wff,
    const float* __restrict__ Wlm, char* __restrict__ ws)
{
    int g = blockIdx.x * 256 + threadIdx.x;
    __hip_bfloat16* wkqv = (__hip_bfloat16*)(ws + WS_WKQV);
    __hip_bfloat16* wff  = (__hip_bfloat16*)(ws + WS_WFF);
    __hip_bfloat16* wlm  = (__hip_bfloat16*)(ws + WS_WLM);
    if (g < 40960) {
        int n = g >> 7, e = g & 127;
        float v = 0.f;
        if (e < Ee) {
            if (n < 100)      v = Wk[n * Ee + e] * 14.4269504089f; // 10 * log2(e)
            else if (n < 200) v = Wq[(n - 100) * Ee + e];
            else if (n < 300) v = Wv[(n - 200) * Ee + e];
        }
        wkqv[g] = __float2bfloat16(v);
    } else if (g < 57344) {
        int gg = g - 40960; int n = gg >> 7, e = gg & 127;
        float v = (e < Ee && n < Ee) ? Wff[n * Ee + e] : 0.f;
        wff[gg] = __float2bfloat16(v);
    } else {
        int gg = g - 57344; int n = gg >> 7, e = gg & 127;
        float v = (e < Ee && n < Vv) ? Wlm[n * Ee + e] : 0.f;
        wlm[gg] = __float2bfloat16(v);
    }
}

__global__ __launch_bounds__(256, 3) void gpt_main(
    const int* __restrict__ idx, const int* __restrict__ targets,
    const float* __restrict__ tok_emb, const float* __restrict__ pos_emb,
    const float* __restrict__ b_ff, const float* __restrict__ b_lm,
    const char* __restrict__ ws, float* __restrict__ out,
    float* __restrict__ loss_part)
{
    __shared__ __attribute__((aligned(16))) __hip_bfloat16 sh[22400];  // 44.8 KB -> 3 blocks/CU
    __shared__ int tok_s[Tt];
    __shared__ float bsum;

    const int b    = blockIdx.x;
    const int tid  = threadIdx.x;
    const int wave = tid >> 6;
    const int ln   = tid & 15;
    const int quad = (tid >> 4) & 3;

    // ---- P1: stage idx; zero ALL of sh; fill x = tok_emb[idx]+pos_emb ----
    if (tid < Tt) tok_s[tid] = idx[b * Tt + tid];
    if (tid == 0) bsum = 0.f;
    {
        const uint4 z4 = make_uint4(0u, 0u, 0u, 0u);
        for (int i = tid; i < 2800; i += 256) ((uint4*)sh)[i] = z4;
    }
    __syncthreads();
    for (int i = tid; i < Tt * 25; i += 256) {
        int r = i / 25, c4 = (i - r * 25) * 4;
        const float4 te = *(const float4*)&tok_emb[tok_s[r] * Ee + c4];
        const float4 pe = *(const float4*)&pos_emb[r * Ee + c4];
        ushort4 o;
        o.x = bfbits(te.x + pe.x); o.y = bfbits(te.y + pe.y);
        o.z = bfbits(te.z + pe.z); o.w = bfbits(te.w + pe.w);
        *(ushort4*)&sh[r * XSTR + c4] = o;
    }
    __syncthreads();

    // ---- P2: kqv = x @ Wkqv^T via MFMA (4 waves x 5 n-tiles x 4 m-tiles) ----
    {
        const __hip_bfloat16* wkqv = (const __hip_bfloat16*)(ws + WS_WKQV);
        f32x4 acc[5][4];
#pragma unroll
        for (int j = 0; j < 5; ++j)
#pragma unroll
            for (int mt = 0; mt < 4; ++mt) {
                f32x4 z = {0.f, 0.f, 0.f, 0.f};
                acc[j][mt] = z;
            }
#pragma unroll
        for (int kt = 0; kt < 4; ++kt) {
            v8bf a[4];
#pragma unroll
            for (int mt = 0; mt < 4; ++mt)
                a[mt] = (mt < 3 || ln < 2)
                      ? *(const v8bf*)&sh[(mt * 16 + ln) * XSTR + kt * 32 + quad * 8]
                      : bzero8();
#pragma unroll
            for (int j = 0; j < 5; ++j) {
                int nt = wave * 5 + j;
                v8bf bfr = *(const v8bf*)&wkqv[(nt * 16 + ln) * 128 + kt * 32 + quad * 8];
#pragma unroll
                for (int mt = 0; mt < 4; ++mt)
                    acc[j][mt] = __builtin_amdgcn_mfma_f32_16x16x32_bf16(a[mt], bfr, acc[j][mt], 0, 0, 0);
            }
        }
        __syncthreads();   // all x reads done; region1 becomes qb
        // re-zero qb d-pads (elements 5..7 of each 8-elem row)
        for (int i = tid; i < 1000; i += 256) {
            *(unsigned short*)&sh[i * 8 + 5] = 0;
            *(unsigned*)&sh[i * 8 + 6] = 0;
        }
        // C/D: col(n)=ln, row(m)=quad*4+r
#pragma unroll
        for (int j = 0; j < 5; ++j) {
            int n = (wave * 5 + j) * 16 + ln;
            if (n < 300) {
                int mat = n / 100;
                int jj  = n - mat * 100;
                int h   = jj / 5, d = jj - (jj / 5) * 5;
#pragma unroll
                for (int mt = 0; mt < 4; ++mt)
#pragma unroll
                    for (int r = 0; r < 4; ++r) {
                        int m = mt * 16 + quad * 4 + r;
                        if (m < Tt) {
                            __hip_bfloat16 val = __float2bfloat16(acc[j][mt][r]);
                            if (mat == 0)      sh[R2 + (h * 50 + m) * 8 + d] = val;  // kb
                            else if (mat == 1) sh[(h * 50 + m) * 8 + d] = val;       // qb
                            else               sh[R3 + (h * 5 + d) * 64 + m] = val;  // vtb
                        }
                    }
            }
        }
    }
    __syncthreads();

    // ---- P3: attention fully in-register, no cross-lane ops.
    //  Orientation-2 (A=k,B=q): D2[t][s], t=quad*4+r, s=ln -> masked exp ->
    //  tile-sum over t-tiles -> ones-MFMA (esum as A-frag) puts denom[s] at
    //  s = ns*16+quad*4+r in reg r -> rd folds into PV's v-fragment in-register.
    //  Orientation-1 (A=q,B=k): D1[s][t] -> masked exp = PV A-frag directly. ----
    unsigned attp[5][8];
    {
        v4s ones4; ones4[0] = ones4[1] = ones4[2] = ones4[3] = (short)0x3F80; // bf16 1.0
#pragma unroll
        for (int hj = 0; hj < 5; ++hj) {
            const int h = wave * 5 + hj;
            v8bf qf[4], kf[4];
#pragma unroll
            for (int i = 0; i < 4; ++i) {
                int row = i * 16 + ln;
                qf[i] = (quad == 0) ? *(const v8bf*)&sh[(h * 50 + row) * 8] : bzero8();
                kf[i] = (quad == 0) ? *(const v8bf*)&sh[R2 + (h * 50 + row) * 8] : bzero8();
            }
            // --- denominators ---
            float rdv[4][4];
#pragma unroll
            for (int ns = 0; ns < 4; ++ns) {
                float esum[4] = {0.f, 0.f, 0.f, 0.f};
#pragma unroll
                for (int mt = ns; mt < 4; ++mt) {
                    f32x4 z = {0.f, 0.f, 0.f, 0.f};
                    f32x4 t2 = __builtin_amdgcn_mfma_f32_16x16x32_bf16(kf[mt], qf[ns], z, 0, 0, 0);
                    int s = ns * 16 + ln;
#pragma unroll
                    for (int r = 0; r < 4; ++r) {
                        int t = mt * 16 + quad * 4 + r;
                        float x = __builtin_amdgcn_exp2f(t2[r]);
                        esum[r] += (t >= s && t < Tt && s < Tt) ? x : 0.f;
                    }
                }
                v4s af;
                af[0] = (short)bfbits(esum[0]); af[1] = (short)bfbits(esum[1]);
                af[2] = (short)bfbits(esum[2]); af[3] = (short)bfbits(esum[3]);
                f32x4 z = {0.f, 0.f, 0.f, 0.f};
                f32x4 dres = mfma_16x16x16_bf16(af, ones4, z);
#pragma unroll
                for (int r = 0; r < 4; ++r) {
                    int s = ns * 16 + quad * 4 + r;
                    rdv[ns][r] = (s < Tt) ? __builtin_amdgcn_rcpf(dres[r]) : 0.f;
                }
            }
            // --- PV ---
            f32x4 pac[4];
#pragma unroll
            for (int mt = 0; mt < 4; ++mt) { f32x4 z = {0.f, 0.f, 0.f, 0.f}; pac[mt] = z; }
#pragma unroll
            for (int ms = 0; ms < 4; ++ms) {
                v4s braw;
                if (ln < Dd) braw = *(const v4s*)&sh[R3 + (h * 5 + ln) * 64 + ms * 16 + quad * 4];
                else { v4s z = {0, 0, 0, 0}; braw = z; }
                v4s bvt;
#pragma unroll
                for (int j = 0; j < 4; ++j)
                    bvt[j] = (short)bfbits(bf2f(braw[j]) * rdv[ms][j]);
#pragma unroll
                for (int u = 0; u < 4 - ms; ++u) {
                    f32x4 z = {0.f, 0.f, 0.f, 0.f};
                    f32x4 t1 = __builtin_amdgcn_mfma_f32_16x16x32_bf16(qf[ms], kf[ms + u], z, 0, 0, 0);
                    int t = (ms + u) * 16 + ln;
                    v4s af;
#pragma unroll
                    for (int r = 0; r < 4; ++r) {
                        int s = ms * 16 + quad * 4 + r;
                        float x = __builtin_amdgcn_exp2f(t1[r]);
                        x = (t >= s && t < Tt && s < Tt) ? x : 0.f;
                        af[r] = (short)bfbits(x);
                    }
                    pac[ms + u] = mfma_16x16x16_bf16(af, bvt, pac[ms + u]);
                }
            }
            // C/D of 16x16x16: col n=ln (d), row m=quad*4+r -> t = mt*16+quad*4+r
#pragma unroll
            for (int mt = 0; mt < 4; ++mt) {
                attp[hj][mt * 2]     = pack2(pac[mt][0], pac[mt][1]);
                attp[hj][mt * 2 + 1] = pack2(pac[mt][2], pac[mt][3]);
            }
        }
    }
    __syncthreads();   // all qb/kb/vtb reads done; region1 becomes attnbuf

    // ---- dump attn registers -> attnbuf (region1, [50][136]) ----
#pragma unroll
    for (int hj = 0; hj < 5; ++hj) {
        int col = (wave * 5 + hj) * 5 + ln;
#pragma unroll
        for (int mt = 0; mt < 4; ++mt)
#pragma unroll
            for (int r = 0; r < 4; ++r) {
                int t = mt * 16 + quad * 4 + r;
                if (ln < Dd && t < Tt) {
                    unsigned w = attp[hj][mt * 2 + (r >> 1)];
                    unsigned short v = (unsigned short)((r & 1) ? (w >> 16) : (w & 0xffff));
                    *(unsigned short*)&sh[t * XSTR + col] = v;
                }
            }
    }
    __syncthreads();

    // ---- P4: h = relu(attn @ Wff^T + b_ff); attnbuf(region1) -> h(region2) ----
    {
        const __hip_bfloat16* wff = (const __hip_bfloat16*)(ws + WS_WFF);
        f32x4 fac[2][4];
#pragma unroll
        for (int u = 0; u < 2; ++u)
#pragma unroll
            for (int mt = 0; mt < 4; ++mt) {
                f32x4 z = {0.f, 0.f, 0.f, 0.f};
                fac[u][mt] = z;
            }
        const int nn = (wave < 3) ? 2 : 1;
#pragma unroll
        for (int kt = 0; kt < 4; ++kt) {
            v8bf a[4];
#pragma unroll
            for (int mt = 0; mt < 4; ++mt)
                a[mt] = (mt < 3 || ln < 2)
                      ? *(const v8bf*)&sh[(mt * 16 + ln) * XSTR + kt * 32 + quad * 8]
                      : bzero8();
#pragma unroll
            for (int u = 0; u < 2; ++u) {
                if (u < nn) {
                    int nt = wave + u * 4;
                    v8bf bfr = *(const v8bf*)&wff[(nt * 16 + ln) * 128 + kt * 32 + quad * 8];
#pragma unroll
                    for (int mt = 0; mt < 4; ++mt)
                        fac[u][mt] = __builtin_amdgcn_mfma_f32_16x16x32_bf16(a[mt], bfr, fac[u][mt], 0, 0, 0);
                }
            }
        }
#pragma unroll
        for (int u = 0; u < 2; ++u) {
            if (u < nn) {
                int n = (wave + u * 4) * 16 + ln;
                if (n < Ee) {
                    float bias = b_ff[n];
#pragma unroll
                    for (int mt = 0; mt < 4; ++mt)
#pragma unroll
                        for (int r = 0; r < 4; ++r) {
                            int m = mt * 16 + quad * 4 + r;
                            if (m < Tt) {
                                float v = fac[u][mt][r] + bias;
                                sh[R2 + m * XSTR + n] = __float2bfloat16(v > 0.f ? v : 0.f);
                            }
                        }
                }
            }
        }
    }
    __syncthreads();

    // ---- P5: logits = h @ Wlm^T + b_lm; h(region2) -> out + logits f32(region1) ----
    {
        const __hip_bfloat16* wlm = (const __hip_bfloat16*)(ws + WS_WLM);
        float* lgl = (float*)sh;   // [50][68] f32 = 13600B
#pragma unroll
        for (int i = 0; i < 5; ++i) {
            int job = wave + i * 4;            // 0..19
            int mt = job / 5, nt = job - (job / 5) * 5;
            f32x4 acc = {0.f, 0.f, 0.f, 0.f};
#pragma unroll
            for (int kt = 0; kt < 4; ++kt) {
                v8bf a = (mt < 3 || ln < 2)
                       ? *(const v8bf*)&sh[R2 + (mt * 16 + ln) * XSTR + kt * 32 + quad * 8]
                       : bzero8();
                v8bf bf = *(const v8bf*)&wlm[(nt * 16 + ln) * 128 + kt * 32 + quad * 8];
                acc = __builtin_amdgcn_mfma_f32_16x16x32_bf16(a, bf, acc, 0, 0, 0);
            }
            int n = nt * 16 + ln;
            if (n < Vv) {
                float bias = b_lm[n];
#pragma unroll
                for (int r = 0; r < 4; ++r) {
                    int m = mt * 16 + quad * 4 + r;
                    if (m < Tt) {
                        float v = acc[r] + bias;
                        out[(b * Tt + m) * Vv + n] = v;
                        lgl[m * 68 + n] = v;
                    }
                }
            }
        }
    }
    __syncthreads();

    // ---- P6: loss; 4 lanes per token row; per-block partial -> ws array ----
    if (tid < 200) {
        int r = tid >> 2, lv = tid & 3;
        const float* row = (const float*)sh + r * 68;
        float mx = -3.0e38f;
        for (int v = lv; v < Vv; v += 4) mx = fmaxf(mx, row[v]);
        mx = fmaxf(mx, __shfl_xor(mx, 1));
        mx = fmaxf(mx, __shfl_xor(mx, 2));
        float sum = 0.f;
        for (int v = lv; v < Vv; v += 4)
            sum += __builtin_amdgcn_exp2f((row[v] - mx) * 1.4426950408889634f);
        sum += __shfl_xor(sum, 1);
        sum += __shfl_xor(sum, 2);
        if (lv == 0) {
            float lse = mx + 0.69314718055994531f * log2f(sum);
            int tgt = targets[b * Tt + r];
            atomicAdd(&bsum, lse - row[tgt]);
        }
    }
    __syncthreads();
    if (tid == 0) loss_part[b] = bsum;   // plain store; no global atomics
}

__global__ __launch_bounds__(256) void loss_reduce(const float* __restrict__ lp,
                                                   float* __restrict__ out)
{
    __shared__ float wsum[4];
    int tid = threadIdx.x;
    float s = 0.f;
    for (int i = tid; i < Bb; i += 256) s += lp[i];
    s += __shfl_xor(s, 1);  s += __shfl_xor(s, 2);  s += __shfl_xor(s, 4);
    s += __shfl_xor(s, 8);  s += __shfl_xor(s, 16); s += __shfl_xor(s, 32);
    if ((tid & 63) == 0) wsum[tid >> 6] = s;
    __syncthreads();
    if (tid == 0)
        out[Bb * Tt * Vv] = (wsum[0] + wsum[1] + wsum[2] + wsum[3]) * (1.0f / (float)(Bb * Tt));
}

extern "C" void kernel_launch(void* const* d_in, const int* in_sizes, int n_in,
                              void* d_out, int out_size, void* d_ws, size_t ws_size,
                              hipStream_t stream)
{
    const int* idx     = (const int*)d_in[0];
    const int* targets = (const int*)d_in[1];
    const float* tok_emb = (const float*)d_in[2];
    const float* pos_emb = (const float*)d_in[3];
    const float* Wk  = (const float*)d_in[4];
    const float* Wq  = (const float*)d_in[5];
    const float* Wv  = (const float*)d_in[6];
    const float* Wff = (const float*)d_in[7];
    const float* bff = (const float*)d_in[8];
    const float* Wlm = (const float*)d_in[9];
    const float* blm = (const float*)d_in[10];
    float* out = (float*)d_out;
    char* ws = (char*)d_ws;
    float* loss_part = (float*)(ws + WS_LPART);

    hipLaunchKernelGGL(prep_kernel, dim3(264), dim3(256), 0, stream, Wk, Wq, Wv, Wff, Wlm, ws);
    hipLaunchKernelGGL(gpt_main, dim3(Bb), dim3(256), 0, stream,
                       idx, targets, tok_emb, pos_emb, bff, blm, (const char*)ws, out, loss_part);
    hipLaunchKernelGGL(loss_reduce, dim3(1), dim3(256), 0, stream, loss_part, out);
}